// Round 11
// baseline (182.678 us; speedup 1.0000x reference)
//
#include <hip/hip_runtime.h>
#include <hip/hip_bf16.h>

#define NPTS 8192
#define NB 4
#define NC 13
#define KTOP 16
#define SR 32          // stripe rows per block == one sorted tile
#define TPB 256        // 32-pt tiles per batch
#define WIN 8          // init-window tiles (256 pts)
#define MARGIN 2e-3f   // >= 2*eps(split-bf16 ~4e-4)
#define EPSC 1e-3f     // extra cull slack
#define SEGCAP 32      // per-(row,wave) segment capacity
#define DCAP 160       // dense candidate cap per row
#define DCAPP 162
#define NCELLS 4096    // 16^3 Morton cells
#define MAXPT 128      // passing-tile list cap

typedef unsigned long long ull;
typedef short s16x8 __attribute__((ext_vector_type(8)));
typedef float f32x16 __attribute__((ext_vector_type(16)));

__device__ __forceinline__ unsigned short bf16rn(float f) {
    unsigned u = __float_as_uint(f);
    return (unsigned short)((u + 0x7fffu + ((u >> 16) & 1u)) >> 16);
}
__device__ __forceinline__ float bf2f(unsigned short h) {
    return __uint_as_float((unsigned)h << 16);
}
__device__ __forceinline__ unsigned spread4(unsigned v) {   // bits -> 0,3,6,9
    return (v & 1u) | ((v & 2u) << 2) | ((v & 4u) << 4) | ((v & 8u) << 6);
}
__device__ __forceinline__ unsigned cellcode(float x, float y, float z) {
    unsigned cx = (unsigned)min(max((int)floorf(x * 2.f) + 8, 0), 15);
    unsigned cy = (unsigned)min(max((int)floorf(y * 2.f) + 8, 0), 15);
    unsigned cz = (unsigned)min(max((int)floorf(z * 2.f) + 8, 0), 15);
    return spread4(cx) | (spread4(cy) << 1) | (spread4(cz) << 2);
}

// ---------------- prep 1: cell histogram + softmax (original order) ----------------
__global__ __launch_bounds__(256) void hist_kernel(
    const float* __restrict__ logits, const float* __restrict__ xyz,
    unsigned* __restrict__ hist, float4* __restrict__ probst)
{
    int gid = blockIdx.x * 256 + threadIdx.x;
    int b = gid >> 13, n = gid & (NPTS - 1);

    const float* xb = xyz + b * 3 * NPTS;
    float x = xb[n], y = xb[NPTS + n], z = xb[2 * NPTS + n];
    atomicAdd(&hist[b * NCELLS + cellcode(x, y, z)], 1u);

    const float* lb = logits + b * NC * NPTS;
    float l[NC];
    float mx = -1e30f;
    #pragma unroll
    for (int c = 0; c < NC; ++c) { l[c] = lb[c * NPTS + n]; mx = fmaxf(mx, l[c]); }
    float sum = 0.f;
    #pragma unroll
    for (int c = 0; c < NC; ++c) { l[c] = __expf(l[c] - mx); sum += l[c]; }
    float inv = 1.0f / sum;
    #pragma unroll
    for (int c = 0; c < NC; ++c) l[c] *= inv;

    float4* dst = probst + (size_t)gid * 4;
    dst[0] = make_float4(l[0], l[1], l[2], l[3]);
    dst[1] = make_float4(l[4], l[5], l[6], l[7]);
    dst[2] = make_float4(l[8], l[9], l[10], l[11]);
    dst[3] = make_float4(l[12], 0.f, 0.f, 0.f);
}

// ---------------- prep 2: exclusive prefix per batch ----------------
__global__ __launch_bounds__(1024) void prefix_kernel(const unsigned* __restrict__ hist,
                                                      unsigned* __restrict__ ofs) {
    __shared__ unsigned s[1024];
    int b = blockIdx.x, t = threadIdx.x;
    unsigned v[4], sum = 0;
    #pragma unroll
    for (int i = 0; i < 4; ++i) { v[i] = hist[b * NCELLS + t * 4 + i]; sum += v[i]; }
    s[t] = sum; __syncthreads();
    for (int d = 1; d < 1024; d <<= 1) {
        unsigned u = (t >= d) ? s[t - d] : 0u;
        __syncthreads();
        s[t] += u;
        __syncthreads();
    }
    unsigned base = s[t] - sum;
    #pragma unroll
    for (int i = 0; i < 4; ++i) { ofs[b * NCELLS + t * 4 + i] = base; base += v[i]; }
}

// ---------------- prep 3: scatter into Morton-sorted order ----------------
__global__ __launch_bounds__(256) void scatter_kernel(
    const float* __restrict__ xyz, unsigned* __restrict__ ofs,
    float4* __restrict__ spts, unsigned short* __restrict__ sid)
{
    int gid = blockIdx.x * 256 + threadIdx.x;
    int b = gid >> 13, n = gid & (NPTS - 1);
    const float* xb = xyz + b * 3 * NPTS;
    float x = xb[n], y = xb[NPTS + n], z = xb[2 * NPTS + n];
    float w = -0.5f * (x * x + y * y + z * z);
    unsigned pos = atomicAdd(&ofs[b * NCELLS + cellcode(x, y, z)], 1u);
    spts[b * NPTS + pos] = make_float4(x, y, z, w);
    sid[b * NPTS + pos] = (unsigned short)n;
}

// ---------------- prep 4: per-32pt-tile AABB + split-bf16 features ----------------
__global__ __launch_bounds__(256) void bboxfeat_kernel(
    const float4* __restrict__ spts, float4* __restrict__ bbmin,
    float4* __restrict__ bbmax, unsigned short* __restrict__ featB)
{
    int gt = blockIdx.x * 8 + (threadIdx.x >> 5);   // global tile id (NB*256)
    int l = threadIdx.x & 31;
    float4 p = spts[gt * 32 + l];

    unsigned short hx = bf16rn(p.x), hy = bf16rn(p.y), hz = bf16rn(p.z);
    unsigned short lx = bf16rn(p.x - bf2f(hx)), ly = bf16rn(p.y - bf2f(hy)),
                   lz = bf16rn(p.z - bf2f(hz));
    unsigned short whi = bf16rn(p.w), wlo = bf16rn(p.w - bf2f(whi));
    uint4 f0, f1;
    f0.x = (unsigned)hx | ((unsigned)hy << 16);
    f0.y = (unsigned)hz | ((unsigned)lx << 16);
    f0.z = (unsigned)ly | ((unsigned)lz << 16);
    f0.w = (unsigned)hx | ((unsigned)hy << 16);
    f1.x = (unsigned)hz | ((unsigned)whi << 16);
    f1.y = (unsigned)wlo; f1.z = 0u; f1.w = 0u;
    uint4* fb = (uint4*)(featB + (size_t)(gt * 32 + l) * 16);
    fb[0] = f0; fb[1] = f1;

    float ax = p.x, ay = p.y, az = p.z, bx = p.x, by = p.y, bz = p.z;
    #pragma unroll
    for (int mk = 1; mk < 32; mk <<= 1) {           // 32-lane groups (bit5 untouched)
        ax = fminf(ax, __shfl_xor(ax, mk)); bx = fmaxf(bx, __shfl_xor(bx, mk));
        ay = fminf(ay, __shfl_xor(ay, mk)); by = fmaxf(by, __shfl_xor(by, mk));
        az = fminf(az, __shfl_xor(az, mk)); bz = fmaxf(bz, __shfl_xor(bz, mk));
    }
    if (l == 0) {
        bbmin[gt] = make_float4(ax, ay, az, 0.f);
        bbmax[gt] = make_float4(bx, by, bz, 0.f);
    }
}

// ---------------- kernel B: sorted + culled MFMA top-16 + loss ----------------
// 512 thr = 8 waves; stripe = 32 sorted queries = one tile. grid = 1024.
__global__ __launch_bounds__(512, 6) void topk_loss_kernel(
    const float4* __restrict__ spts, const unsigned short* __restrict__ sid,
    const float4* __restrict__ bbmin, const float4* __restrict__ bbmax,
    const unsigned short* __restrict__ featB, const float* __restrict__ rgb,
    const float4* __restrict__ probst, float* __restrict__ partials)
{
    __shared__ __align__(16) char smem[48960];
    float*          s_ds   = (float*)smem;                    // [32][162] f32
    unsigned short* s_di   = (unsigned short*)(smem + 20736); // [32][162] u16
    unsigned short* s_seg  = (unsigned short*)(smem + 31104); // [32][8][32] u16
    unsigned short* s_scnt = (unsigned short*)(smem + 47488); // [32][8] u16
    float*          s_thr  = (float*)(smem + 48000);          // [32] f32
    float4*         s_q4   = (float4*)(smem + 48128);         // [32] f4
    unsigned short* s_pt   = (unsigned short*)(smem + 48640); // [128] u16
    unsigned*       s_tm   = (unsigned*)(smem + 48896);       // [8] u32
    float*          s_wred = (float*)(smem + 48928);          // [8] f32
    float*          s_bk   = (float*)smem;                    // overlay [0,32768)

    const int tid = threadIdx.x;
    const int w = tid >> 6, lane = tid & 63;
    const int l31 = lane & 31, h = lane >> 5;
    const int b = blockIdx.x >> 8;
    const int T = blockIdx.x & 255;                 // stripe == sorted tile T
    const int nbase = T * SR;
    const int sb = b * NPTS;
    const int tw0 = min(max(T - 3, 0), TPB - WIN);

    // ---- A fragment (sorted queries, split-bf16) + q4 stash ----
    const float4 Q0 = spts[sb + nbase + l31];
    if (w == 0 && h == 0) s_q4[l31] = Q0;
    unsigned short qhx = bf16rn(Q0.x), qhy = bf16rn(Q0.y), qhz = bf16rn(Q0.z);
    unsigned short qlx = bf16rn(Q0.x - bf2f(qhx)), qly = bf16rn(Q0.y - bf2f(qhy)),
                   qlz = bf16rn(Q0.z - bf2f(qhz));
    const unsigned short ONE = 0x3F80;
    union { unsigned short u[8]; s16x8 v; } af;
    if (h == 0) {
        af.u[0] = qhx; af.u[1] = qhy; af.u[2] = qhz; af.u[3] = qhx;
        af.u[4] = qhy; af.u[5] = qhz; af.u[6] = qlx; af.u[7] = qly;
    } else {
        af.u[0] = qlz; af.u[1] = ONE; af.u[2] = ONE; af.u[3] = 0;
        af.u[4] = 0;   af.u[5] = 0;   af.u[6] = 0;   af.u[7] = 0;
    }
    f32x16 cz;
    #pragma unroll
    for (int i = 0; i < 16; ++i) cz[i] = 0.f;
    const unsigned short* fB = featB + (size_t)sb * 16;

    // ---- pass 1: one window tile per wave via MFMA ----
    {
        int t = tw0 + w;
        s16x8 bf = *(const s16x8*)(fB + (size_t)(t * 32 + l31) * 16 + h * 8);
        f32x16 c = __builtin_amdgcn_mfma_f32_32x32x16_bf16(af.v, bf, cz, 0, 0, 0);
        #pragma unroll
        for (int r = 0; r < 16; ++r) s_bk[(w * 16 + r) * 64 + lane] = c[r];
    }
    __syncthreads();                                // B1

    // ---- thresholds: 8-wave col-max merge; min over 8 buckets of top-2 ----
    float thr[16];
    #pragma unroll
    for (int r = 0; r < 16; ++r) {
        float m = s_bk[r * 64 + lane];
        #pragma unroll
        for (int w2 = 1; w2 < 8; ++w2) m = fmaxf(m, s_bk[(w2 * 16 + r) * 64 + lane]);
        float m1 = m, m2 = -3.0e38f;
        #pragma unroll
        for (int mk = 8; mk <= 16; mk <<= 1) {
            float p1 = __shfl_xor(m1, mk), p2 = __shfl_xor(m2, mk);
            float lo = fminf(m1, p1);
            m1 = fmaxf(m1, p1);
            m2 = fmaxf(lo, fmaxf(m2, p2));
        }
        #pragma unroll
        for (int mk = 1; mk < 8; mk <<= 1) m2 = fminf(m2, __shfl_xor(m2, mk));
        thr[r] = m2 - MARGIN;
        if (w == 0 && l31 == 0) s_thr[(r & 3) + 8 * (r >> 2) + 4 * h] = thr[r];
    }
    __syncthreads();                                // B2 (overlay dead)

    // ---- AABB cull: thread pair per tile, 16 rows each ----
    {
        const int ct = (tid >> 1) & 255;            // tile 0..255
        const int rb0 = (tid & 1) * 16;
        float4 bn = bbmin[b * TPB + ct], bx = bbmax[b * TPB + ct];
        bool p16 = false;
        #pragma unroll
        for (int i = 0; i < 16; ++i) {
            int rr = rb0 + i;
            float4 q4 = s_q4[rr];
            float thrC = s_thr[rr] - EPSC;
            float dc = fmaf(-2.f, thrC, -2.f * q4.w) * 1.0001f + 1e-6f;
            float dx = fmaxf(fmaxf(bn.x - q4.x, q4.x - bx.x), 0.f);
            float dy = fmaxf(fmaxf(bn.y - q4.y, q4.y - bx.y), 0.f);
            float dz = fmaxf(fmaxf(bn.z - q4.z, q4.z - bx.z), 0.f);
            p16 |= (fmaf(dx, dx, fmaf(dy, dy, dz * dz)) <= dc);
        }
        int full = (int)p16 | __shfl_xor((int)p16, 1);
        if (ct >= tw0 && ct < tw0 + WIN) full = 0;  // window scanned anyway
        ull bal = __ballot(full != 0);
        ull x = bal & 0x5555555555555555ull;        // compress even bit-pairs
        x = (x | (x >> 1))  & 0x3333333333333333ull;
        x = (x | (x >> 2))  & 0x0f0f0f0f0f0f0f0full;
        x = (x | (x >> 4))  & 0x00ff00ff00ff00ffull;
        x = (x | (x >> 8))  & 0x0000ffff0000ffffull;
        x = (x | (x >> 16));
        if (lane == 0) s_tm[w] = (unsigned)(x & 0xffffffffull);
    }
    __syncthreads();                                // B3

    // ---- deterministic passing-tile list ----
    int ntile;
    {
        unsigned mk[8]; int tot = 0, base = 0;
        #pragma unroll
        for (int w2 = 0; w2 < 8; ++w2) {
            mk[w2] = s_tm[w2];
            if (w2 < w) base += __popc(mk[w2]);
            tot += __popc(mk[w2]);
        }
        ntile = min(tot, MAXPT);
        if (h == 0 && ((mk[w] >> l31) & 1u)) {
            int pos = base + __popc(mk[w] & ((1u << l31) - 1u));
            if (pos < MAXPT) s_pt[pos] = (unsigned short)(w * 32 + l31);
        }
    }
    __syncthreads();                                // B4

    // ---- pass 2: MFMA + segment append over window + passing tiles ----
    int cntr[16];
    #pragma unroll
    for (int r = 0; r < 16; ++r) cntr[r] = 0;
    const unsigned ltmask = (1u << l31) - 1u;

    #define DO_TILE(TT)                                                         \
    {                                                                           \
        int t_ = (TT);                                                          \
        s16x8 bf = *(const s16x8*)(fB + (size_t)(t_ * 32 + l31) * 16 + h * 8);  \
        f32x16 c = __builtin_amdgcn_mfma_f32_32x32x16_bf16(af.v, bf, cz, 0, 0, 0); \
        _Pragma("unroll")                                                       \
        for (int r = 0; r < 16; ++r) {                                          \
            bool pass = (c[r] >= thr[r]);                                       \
            ull mask = __ballot(pass);                                          \
            if (mask) {                                                         \
                unsigned mh = (unsigned)(h ? (mask >> 32) : mask);              \
                if (pass) {                                                     \
                    int row = (r & 3) + 8 * (r >> 2) + 4 * h;                   \
                    int slot = cntr[r] + __popc(mh & ltmask);                   \
                    if (slot < SEGCAP)                                          \
                        s_seg[(row * 8 + w) * SEGCAP + slot] =                  \
                            (unsigned short)(t_ * 32 + l31);                    \
                }                                                               \
                cntr[r] += __popc(mh);                                          \
            }                                                                   \
        }                                                                       \
    }

    DO_TILE(tw0 + w);
    for (int j = w; j < ntile; j += 8) DO_TILE((int)s_pt[j]);
    #undef DO_TILE

    if (l31 == 0) {
        #pragma unroll
        for (int r = 0; r < 16; ++r) {
            int row = (r & 3) + 8 * (r >> 2) + 4 * h;
            s_scnt[row * 8 + w] = (unsigned short)min(cntr[r], SEGCAP);
        }
    }
    __syncthreads();                                // B5

    // ---- compact + exact fp32 rescore (16 lanes per row) ----
    const int row = tid >> 4, i0 = tid & 15;
    const int nrow = nbase + row;
    int cw[8], off[8], cnt = 0;
    #pragma unroll
    for (int w2 = 0; w2 < 8; ++w2) {
        cw[w2] = s_scnt[row * 8 + w2];
        off[w2] = cnt; cnt += cw[w2];
    }
    cnt = min(cnt, DCAP);

    const float4 Q = spts[sb + nrow];
    #pragma unroll
    for (int w2 = 0; w2 < 8; ++w2) {
        for (int k = i0; k < cw[w2]; k += 16) {
            int j = off[w2] + k;
            if (j < DCAP) {
                int p = s_seg[(row * 8 + w2) * SEGCAP + k];
                float4 P = spts[sb + p];
                float s = fmaf(Q.x, P.x, fmaf(Q.y, P.y, fmaf(Q.z, P.z, P.w)));
                s_ds[row * DCAPP + j] = s;
                s_di[row * DCAPP + j] = (unsigned short)p;
            }
        }
    }
    __syncthreads();                                // B6

    // ---- rank-count selection + loss ----
    const float* rb = rgb + b * 3 * NPTS;
    const int cid = sid[sb + nrow];
    float crx = rb[cid], cry = rb[NPTS + cid], crz = rb[2 * NPTS + cid];
    const float4* cp = probst + (size_t)(sb + cid) * 4;
    float4 cp0 = cp[0], cp1 = cp[1], cp2 = cp[2], cp3 = cp[3];

    float acc = 0.f;
    for (int j = i0; j < cnt; j += 16) {
        float sj = s_ds[row * DCAPP + j];
        unsigned pj = s_di[row * DCAPP + j];
        int rank = 0;
        for (int j2 = 0; j2 < cnt; ++j2) {
            float s2 = s_ds[row * DCAPP + j2];
            unsigned p2 = s_di[row * DCAPP + j2];
            rank += (int)((s2 > sj) | ((s2 == sj) & (p2 < pj)));
        }
        if (rank < KTOP) {
            int m = sid[sb + pj];
            float nrx = rb[m], nry = rb[NPTS + m], nrz = rb[2 * NPTS + m];
            const float4* np4 = probst + (size_t)(sb + m) * 4;
            float4 q0 = np4[0], q1 = np4[1], q2 = np4[2], q3 = np4[3];
            float dx = crx - nrx, dy = cry - nry, dz = crz - nrz;
            float rd = sqrtf(fmaf(dx, dx, fmaf(dy, dy, dz * dz)));
            float pd = fabsf(cp0.x-q0.x)+fabsf(cp0.y-q0.y)+fabsf(cp0.z-q0.z)+fabsf(cp0.w-q0.w)
                     + fabsf(cp1.x-q1.x)+fabsf(cp1.y-q1.y)+fabsf(cp1.z-q1.z)+fabsf(cp1.w-q1.w)
                     + fabsf(cp2.x-q2.x)+fabsf(cp2.y-q2.y)+fabsf(cp2.z-q2.z)+fabsf(cp2.w-q2.w)
                     + fabsf(cp3.x-q3.x)+fabsf(cp3.y-q3.y)+fabsf(cp3.z-q3.z)+fabsf(cp3.w-q3.w);
            acc = fmaf(__expf(-10.0f * rd), pd, acc);
        }
    }

    #pragma unroll
    for (int offv = 32; offv > 0; offv >>= 1) acc += __shfl_down(acc, offv);
    if (lane == 0) s_wred[w] = acc;
    __syncthreads();
    if (tid == 0) {
        float bs = 0.f;
        #pragma unroll
        for (int i = 0; i < 8; ++i) bs += s_wred[i];
        partials[blockIdx.x] = bs;
    }
}

// ---------------- kernel C: final reduce (1024 partials) ----------------
__global__ __launch_bounds__(256) void reduce_kernel(const float* __restrict__ partials,
                                                     float* __restrict__ out) {
    __shared__ float s[256];
    int tid = threadIdx.x;
    s[tid] = partials[tid] + partials[tid + 256] + partials[tid + 512] + partials[tid + 768];
    __syncthreads();
    if (tid < 128) s[tid] += s[tid + 128];
    __syncthreads();
    if (tid < 64) {
        float x = s[tid] + s[tid + 64];
        for (int off = 32; off > 0; off >>= 1) x += __shfl_down(x, off);
        if (tid == 0) out[0] = x * (1.0f / (float)(NB * NPTS * KTOP));
    }
}

extern "C" void kernel_launch(void* const* d_in, const int* in_sizes, int n_in,
                              void* d_out, int out_size, void* d_ws, size_t ws_size,
                              hipStream_t stream) {
    (void)in_sizes; (void)n_in; (void)out_size; (void)ws_size;
    const float* logits = (const float*)d_in[0];
    const float* xyz    = (const float*)d_in[1];
    const float* rgb    = (const float*)d_in[2];

    // workspace ~3.73 MB
    float4* probst = (float4*)d_ws;                                  // 2 MB
    float4* spts   = probst + (size_t)NB * NPTS * 4;                 // 512 KB
    unsigned short* featB = (unsigned short*)(spts + NB * NPTS);     // 1 MB
    float4* bbmin  = (float4*)(featB + (size_t)NB * NPTS * 16);      // 16 KB
    float4* bbmax  = bbmin + NB * TPB;                               // 16 KB
    unsigned* hist = (unsigned*)(bbmax + NB * TPB);                  // 64 KB
    unsigned* ofs  = hist + NB * NCELLS;                             // 64 KB
    unsigned short* sid = (unsigned short*)(ofs + NB * NCELLS);      // 64 KB
    float* partials = (float*)(sid + NB * NPTS);                     // 4 KB

    hipMemsetAsync(hist, 0, (size_t)NB * NCELLS * sizeof(unsigned), stream);
    hist_kernel<<<NB * NPTS / 256, 256, 0, stream>>>(logits, xyz, hist, probst);
    prefix_kernel<<<NB, 1024, 0, stream>>>(hist, ofs);
    scatter_kernel<<<NB * NPTS / 256, 256, 0, stream>>>(xyz, ofs, spts, sid);
    bboxfeat_kernel<<<NB * TPB / 8, 256, 0, stream>>>(spts, bbmin, bbmax, featB);
    topk_loss_kernel<<<NB * TPB, 512, 0, stream>>>(spts, sid, bbmin, bbmax,
                                                   featB, rgb, probst, partials);
    reduce_kernel<<<1, 256, 0, stream>>>(partials, (float*)d_out);
}

// Round 12
// 126.452 us; speedup vs baseline: 1.4447x; 1.4447x over previous
//
#include <hip/hip_runtime.h>
#include <hip/hip_bf16.h>

#define NPTS 8192
#define NB 4
#define NC 13
#define KTOP 16
#define SR 32          // stripe rows per block == one sorted tile
#define TPB 256        // 32-pt tiles per batch
#define WIN 8          // threshold window tiles (256 near pts)
#define MARGIN 2e-3f   // >= 2*eps(split-bf16 ~4e-4)
#define SEGCAP 24      // per-(row,wave) segment capacity
#define DCAP 128       // dense candidate cap per row
#define DCAPP 130
#define NCELLS 4096    // 16^3 Morton cells

typedef unsigned long long ull;
typedef short s16x8 __attribute__((ext_vector_type(8)));
typedef float f32x16 __attribute__((ext_vector_type(16)));

__device__ __forceinline__ unsigned short bf16rn(float f) {
    unsigned u = __float_as_uint(f);
    return (unsigned short)((u + 0x7fffu + ((u >> 16) & 1u)) >> 16);
}
__device__ __forceinline__ float bf2f(unsigned short h) {
    return __uint_as_float((unsigned)h << 16);
}
__device__ __forceinline__ unsigned spread4(unsigned v) {   // bits -> 0,3,6,9
    return (v & 1u) | ((v & 2u) << 2) | ((v & 4u) << 4) | ((v & 8u) << 6);
}
__device__ __forceinline__ unsigned cellcode(float x, float y, float z) {
    unsigned cx = (unsigned)min(max((int)floorf(x * 2.f) + 8, 0), 15);
    unsigned cy = (unsigned)min(max((int)floorf(y * 2.f) + 8, 0), 15);
    unsigned cz = (unsigned)min(max((int)floorf(z * 2.f) + 8, 0), 15);
    return spread4(cx) | (spread4(cy) << 1) | (spread4(cz) << 2);
}

// ---------------- prep 1: cell histogram + softmax (original order) ----------------
__global__ __launch_bounds__(256) void hist_kernel(
    const float* __restrict__ logits, const float* __restrict__ xyz,
    unsigned* __restrict__ hist, float4* __restrict__ probst)
{
    int gid = blockIdx.x * 256 + threadIdx.x;
    int b = gid >> 13, n = gid & (NPTS - 1);

    const float* xb = xyz + b * 3 * NPTS;
    float x = xb[n], y = xb[NPTS + n], z = xb[2 * NPTS + n];
    atomicAdd(&hist[b * NCELLS + cellcode(x, y, z)], 1u);

    const float* lb = logits + b * NC * NPTS;
    float l[NC];
    float mx = -1e30f;
    #pragma unroll
    for (int c = 0; c < NC; ++c) { l[c] = lb[c * NPTS + n]; mx = fmaxf(mx, l[c]); }
    float sum = 0.f;
    #pragma unroll
    for (int c = 0; c < NC; ++c) { l[c] = __expf(l[c] - mx); sum += l[c]; }
    float inv = 1.0f / sum;
    #pragma unroll
    for (int c = 0; c < NC; ++c) l[c] *= inv;

    float4* dst = probst + (size_t)gid * 4;
    dst[0] = make_float4(l[0], l[1], l[2], l[3]);
    dst[1] = make_float4(l[4], l[5], l[6], l[7]);
    dst[2] = make_float4(l[8], l[9], l[10], l[11]);
    dst[3] = make_float4(l[12], 0.f, 0.f, 0.f);
}

// ---------------- prep 2: exclusive prefix per batch ----------------
__global__ __launch_bounds__(1024) void prefix_kernel(const unsigned* __restrict__ hist,
                                                      unsigned* __restrict__ ofs) {
    __shared__ unsigned s[1024];
    int b = blockIdx.x, t = threadIdx.x;
    unsigned v[4], sum = 0;
    #pragma unroll
    for (int i = 0; i < 4; ++i) { v[i] = hist[b * NCELLS + t * 4 + i]; sum += v[i]; }
    s[t] = sum; __syncthreads();
    for (int d = 1; d < 1024; d <<= 1) {
        unsigned u = (t >= d) ? s[t - d] : 0u;
        __syncthreads();
        s[t] += u;
        __syncthreads();
    }
    unsigned base = s[t] - sum;
    #pragma unroll
    for (int i = 0; i < 4; ++i) { ofs[b * NCELLS + t * 4 + i] = base; base += v[i]; }
}

// ---------------- prep 3: scatter into Morton order + split-bf16 features ----------------
__global__ __launch_bounds__(256) void scatter_kernel(
    const float* __restrict__ xyz, unsigned* __restrict__ ofs,
    float4* __restrict__ spts, unsigned short* __restrict__ sid,
    unsigned short* __restrict__ featB)
{
    int gid = blockIdx.x * 256 + threadIdx.x;
    int b = gid >> 13, n = gid & (NPTS - 1);
    const float* xb = xyz + b * 3 * NPTS;
    float x = xb[n], y = xb[NPTS + n], z = xb[2 * NPTS + n];
    float w = -0.5f * (x * x + y * y + z * z);
    unsigned pos = atomicAdd(&ofs[b * NCELLS + cellcode(x, y, z)], 1u);
    int sp = b * NPTS + (int)pos;
    spts[sp] = make_float4(x, y, z, w);
    sid[sp] = (unsigned short)n;

    unsigned short hx = bf16rn(x), hy = bf16rn(y), hz = bf16rn(z);
    unsigned short lx = bf16rn(x - bf2f(hx)), ly = bf16rn(y - bf2f(hy)),
                   lz = bf16rn(z - bf2f(hz));
    unsigned short whi = bf16rn(w), wlo = bf16rn(w - bf2f(whi));
    uint4 f0, f1;
    f0.x = (unsigned)hx | ((unsigned)hy << 16);
    f0.y = (unsigned)hz | ((unsigned)lx << 16);
    f0.z = (unsigned)ly | ((unsigned)lz << 16);
    f0.w = (unsigned)hx | ((unsigned)hy << 16);
    f1.x = (unsigned)hz | ((unsigned)whi << 16);
    f1.y = (unsigned)wlo; f1.z = 0u; f1.w = 0u;
    uint4* fb = (uint4*)(featB + (size_t)sp * 16);
    fb[0] = f0; fb[1] = f1;
}

// ---------------- kernel B: window-thr + single MFMA scan + exact top-16 + loss ----------------
// 512 thr = 8 waves; stripe = 32 sorted queries = sorted tile T. grid = NB*TPB.
__global__ __launch_bounds__(512, 8) void topk_loss_kernel(
    const float4* __restrict__ spts, const unsigned short* __restrict__ sid,
    const unsigned short* __restrict__ featB, const float* __restrict__ rgb,
    const float4* __restrict__ probst, float* __restrict__ partials)
{
    __shared__ __align__(16) char smem[37792];
    float*          s_ds   = (float*)smem;                    // [32][130] f32
    unsigned short* s_di   = (unsigned short*)(smem + 16640); // [32][130] u16 (orig ids)
    unsigned short* s_seg  = (unsigned short*)(smem + 24960); // [32][8][24] u16
    unsigned short* s_scnt = (unsigned short*)(smem + 37248); // [32][8] u16
    float*          s_wred = (float*)(smem + 37760);          // [8] f32
    float*          s_bk   = (float*)smem;                    // overlay [0,32768)

    const int tid = threadIdx.x;
    const int w = tid >> 6, lane = tid & 63;
    const int l31 = lane & 31, h = lane >> 5;
    const int b = blockIdx.x >> 8;
    const int T = blockIdx.x & 255;
    const int nbase = T * SR;
    const int sb = b * NPTS;
    const int tw0 = min(max(T - 3, 0), TPB - WIN);  // window includes T

    // ---- A fragment (sorted queries, split-bf16) ----
    const float4 Q0 = spts[sb + nbase + l31];
    unsigned short qhx = bf16rn(Q0.x), qhy = bf16rn(Q0.y), qhz = bf16rn(Q0.z);
    unsigned short qlx = bf16rn(Q0.x - bf2f(qhx)), qly = bf16rn(Q0.y - bf2f(qhy)),
                   qlz = bf16rn(Q0.z - bf2f(qhz));
    const unsigned short ONE = 0x3F80;
    union { unsigned short u[8]; s16x8 v; } af;
    if (h == 0) {
        af.u[0] = qhx; af.u[1] = qhy; af.u[2] = qhz; af.u[3] = qhx;
        af.u[4] = qhy; af.u[5] = qhz; af.u[6] = qlx; af.u[7] = qly;
    } else {
        af.u[0] = qlz; af.u[1] = ONE; af.u[2] = ONE; af.u[3] = 0;
        af.u[4] = 0;   af.u[5] = 0;   af.u[6] = 0;   af.u[7] = 0;
    }
    f32x16 cz;
    #pragma unroll
    for (int i = 0; i < 16; ++i) cz[i] = 0.f;
    const unsigned short* fB = featB + (size_t)sb * 16;

    // ---- window pass: wave w scores window tile tw0+w (256 near points) ----
    {
        int t = tw0 + w;
        s16x8 bf = *(const s16x8*)(fB + (size_t)(t * 32 + l31) * 16 + h * 8);
        f32x16 c = __builtin_amdgcn_mfma_f32_32x32x16_bf16(af.v, bf, cz, 0, 0, 0);
        #pragma unroll
        for (int r = 0; r < 16; ++r) s_bk[(w * 16 + r) * 64 + lane] = c[r];
    }
    __syncthreads();                                // B1

    // ---- thresholds: col-slot max over 8 window tiles; min over 8 buckets of top-2 ----
    // (top-2 of 4 disjoint col-slot maxes => 2 distinct pts/bucket; 16 distinct pts >= thr)
    float thr[16];
    #pragma unroll
    for (int r = 0; r < 16; ++r) {
        float m = s_bk[r * 64 + lane];
        #pragma unroll
        for (int w2 = 1; w2 < 8; ++w2) m = fmaxf(m, s_bk[(w2 * 16 + r) * 64 + lane]);
        float m1 = m, m2 = -3.0e38f;
        #pragma unroll
        for (int mk = 8; mk <= 16; mk <<= 1) {
            float p1 = __shfl_xor(m1, mk), p2 = __shfl_xor(m2, mk);
            float lo = fminf(m1, p1);
            m1 = fmaxf(m1, p1);
            m2 = fmaxf(lo, fmaxf(m2, p2));
        }
        #pragma unroll
        for (int mk = 1; mk < 8; mk <<= 1) m2 = fminf(m2, __shfl_xor(m2, mk));
        thr[r] = m2 - MARGIN;
    }
    __syncthreads();                                // B2 (overlay released)

    // ---- single scan: MFMA + ballot-prefix segment append over ALL tiles ----
    int cntr[16];
    #pragma unroll
    for (int r = 0; r < 16; ++r) cntr[r] = 0;
    const unsigned ltmask = (1u << l31) - 1u;

    for (int t = w; t < TPB; t += 8) {
        s16x8 bf = *(const s16x8*)(fB + (size_t)(t * 32 + l31) * 16 + h * 8);
        f32x16 c = __builtin_amdgcn_mfma_f32_32x32x16_bf16(af.v, bf, cz, 0, 0, 0);
        #pragma unroll
        for (int r = 0; r < 16; ++r) {
            bool pass = (c[r] >= thr[r]);
            ull mask = __ballot(pass);
            if (mask) {                             // wave-uniform SALU branch
                unsigned mh = (unsigned)(h ? (mask >> 32) : mask);
                if (pass) {
                    int row = (r & 3) + 8 * (r >> 2) + 4 * h;
                    int slot = cntr[r] + __popc(mh & ltmask);
                    if (slot < SEGCAP)
                        s_seg[(row * 8 + w) * SEGCAP + slot] =
                            (unsigned short)(t * 32 + l31);
                }
                cntr[r] += __popc(mh);
            }
        }
    }
    if (l31 == 0) {
        #pragma unroll
        for (int r = 0; r < 16; ++r) {
            int row = (r & 3) + 8 * (r >> 2) + 4 * h;
            s_scnt[row * 8 + w] = (unsigned short)min(cntr[r], SEGCAP);
        }
    }
    __syncthreads();                                // B3

    // ---- compact + exact fp32 rescore; store exact score + ORIGINAL id ----
    const int row = tid >> 4, i0 = tid & 15;
    const int nrow = nbase + row;
    int cw[8], off[8], cnt = 0;
    #pragma unroll
    for (int w2 = 0; w2 < 8; ++w2) {
        cw[w2] = s_scnt[row * 8 + w2];
        off[w2] = cnt; cnt += cw[w2];
    }
    cnt = min(cnt, DCAP);

    const float4 Q = spts[sb + nrow];
    #pragma unroll
    for (int w2 = 0; w2 < 8; ++w2) {
        for (int k = i0; k < cw[w2]; k += 16) {
            int j = off[w2] + k;
            if (j < DCAP) {
                int p = s_seg[(row * 8 + w2) * SEGCAP + k];
                float4 P = spts[sb + p];
                float s = fmaf(Q.x, P.x, fmaf(Q.y, P.y, fmaf(Q.z, P.z, P.w)));
                s_ds[row * DCAPP + j] = s;
                s_di[row * DCAPP + j] = sid[sb + p];   // original index
            }
        }
    }
    __syncthreads();                                // B4

    // ---- rank-count selection (orig-idx tie-break = reference order) + loss ----
    const float* rb = rgb + b * 3 * NPTS;
    const int cid = sid[sb + nrow];
    float crx = rb[cid], cry = rb[NPTS + cid], crz = rb[2 * NPTS + cid];
    const float4* cp = probst + (size_t)(sb + cid) * 4;
    float4 cp0 = cp[0], cp1 = cp[1], cp2 = cp[2], cp3 = cp[3];

    float acc = 0.f;
    for (int j = i0; j < cnt; j += 16) {
        float sj = s_ds[row * DCAPP + j];
        unsigned mj = s_di[row * DCAPP + j];
        int rank = 0;
        for (int j2 = 0; j2 < cnt; ++j2) {
            float s2 = s_ds[row * DCAPP + j2];
            unsigned m2 = s_di[row * DCAPP + j2];
            rank += (int)((s2 > sj) | ((s2 == sj) & (m2 < mj)));
        }
        if (rank < KTOP) {                          // exact top-16 member
            int m = (int)mj;
            float nrx = rb[m], nry = rb[NPTS + m], nrz = rb[2 * NPTS + m];
            const float4* np4 = probst + (size_t)(sb + m) * 4;
            float4 q0 = np4[0], q1 = np4[1], q2 = np4[2], q3 = np4[3];
            float dx = crx - nrx, dy = cry - nry, dz = crz - nrz;
            float rd = sqrtf(fmaf(dx, dx, fmaf(dy, dy, dz * dz)));
            float pd = fabsf(cp0.x-q0.x)+fabsf(cp0.y-q0.y)+fabsf(cp0.z-q0.z)+fabsf(cp0.w-q0.w)
                     + fabsf(cp1.x-q1.x)+fabsf(cp1.y-q1.y)+fabsf(cp1.z-q1.z)+fabsf(cp1.w-q1.w)
                     + fabsf(cp2.x-q2.x)+fabsf(cp2.y-q2.y)+fabsf(cp2.z-q2.z)+fabsf(cp2.w-q2.w)
                     + fabsf(cp3.x-q3.x)+fabsf(cp3.y-q3.y)+fabsf(cp3.z-q3.z)+fabsf(cp3.w-q3.w);
            acc = fmaf(__expf(-10.0f * rd), pd, acc);
        }
    }

    #pragma unroll
    for (int offv = 32; offv > 0; offv >>= 1) acc += __shfl_down(acc, offv);
    if (lane == 0) s_wred[w] = acc;
    __syncthreads();
    if (tid == 0) {
        float bs = 0.f;
        #pragma unroll
        for (int i = 0; i < 8; ++i) bs += s_wred[i];
        partials[blockIdx.x] = bs;
    }
}

// ---------------- kernel C: final reduce (1024 partials) ----------------
__global__ __launch_bounds__(256) void reduce_kernel(const float* __restrict__ partials,
                                                     float* __restrict__ out) {
    __shared__ float s[256];
    int tid = threadIdx.x;
    s[tid] = partials[tid] + partials[tid + 256] + partials[tid + 512] + partials[tid + 768];
    __syncthreads();
    if (tid < 128) s[tid] += s[tid + 128];
    __syncthreads();
    if (tid < 64) {
        float x = s[tid] + s[tid + 64];
        for (int off = 32; off > 0; off >>= 1) x += __shfl_down(x, off);
        if (tid == 0) out[0] = x * (1.0f / (float)(NB * NPTS * KTOP));
    }
}

extern "C" void kernel_launch(void* const* d_in, const int* in_sizes, int n_in,
                              void* d_out, int out_size, void* d_ws, size_t ws_size,
                              hipStream_t stream) {
    (void)in_sizes; (void)n_in; (void)out_size; (void)ws_size;
    const float* logits = (const float*)d_in[0];
    const float* xyz    = (const float*)d_in[1];
    const float* rgb    = (const float*)d_in[2];

    // workspace ~3.7 MB
    float4* probst = (float4*)d_ws;                                  // 2 MB
    float4* spts   = probst + (size_t)NB * NPTS * 4;                 // 512 KB
    unsigned short* featB = (unsigned short*)(spts + NB * NPTS);     // 1 MB
    unsigned* hist = (unsigned*)(featB + (size_t)NB * NPTS * 16);    // 64 KB
    unsigned* ofs  = hist + NB * NCELLS;                             // 64 KB
    unsigned short* sid = (unsigned short*)(ofs + NB * NCELLS);      // 64 KB
    float* partials = (float*)(sid + NB * NPTS);                     // 4 KB

    hipMemsetAsync(hist, 0, (size_t)NB * NCELLS * sizeof(unsigned), stream);
    hist_kernel<<<NB * NPTS / 256, 256, 0, stream>>>(logits, xyz, hist, probst);
    prefix_kernel<<<NB, 1024, 0, stream>>>(hist, ofs);
    scatter_kernel<<<NB * NPTS / 256, 256, 0, stream>>>(xyz, ofs, spts, sid, featB);
    topk_loss_kernel<<<NB * TPB, 512, 0, stream>>>(spts, sid, featB, rgb, probst, partials);
    reduce_kernel<<<1, 256, 0, stream>>>(partials, (float*)d_out);
}

// Round 16
// 107.777 us; speedup vs baseline: 1.6950x; 1.1733x over previous
//
#include <hip/hip_runtime.h>
#include <hip/hip_bf16.h>

#define NPTS 8192
#define NB 4
#define NC 13
#define KTOP 16
#define SR 32          // stripe rows per block
#define NT (NPTS/32)   // 256 col-tiles of 32 points
#define MARGIN 2e-3f   // >= 2*eps(split-bf16 ~4e-4)
#define SEGCAP 20      // per-(wave,row) segment capacity (mean ~4)
#define DCAP 128       // dense candidate cap per row (mean ~32)
#define DCAPP 130      // padded stride

typedef unsigned long long ull;
typedef short s16x8 __attribute__((ext_vector_type(8)));
typedef float f32x16 __attribute__((ext_vector_type(16)));

__device__ __forceinline__ unsigned short bf16rn(float f) {   // round-to-nearest-even
    unsigned u = __float_as_uint(f);
    return (unsigned short)((u + 0x7fffu + ((u >> 16) & 1u)) >> 16);
}
__device__ __forceinline__ float bf2f(unsigned short h) {
    return __uint_as_float((unsigned)h << 16);
}

// ---------------- kernel A: split-bf16 feature table + spts + softmax ----------------
__global__ __launch_bounds__(256) void prep_kernel(
    const float* __restrict__ logits, const float* __restrict__ xyz,
    unsigned short* __restrict__ featB, float4* __restrict__ spts,
    float4* __restrict__ probst)
{
    int gid = blockIdx.x * 256 + threadIdx.x;      // 0 .. B*N-1
    int b = gid >> 13, n = gid & (NPTS - 1);

    const float* xb = xyz + b * 3 * NPTS;
    float x = xb[n], y = xb[NPTS + n], z = xb[2 * NPTS + n];
    float wv = -0.5f * (x * x + y * y + z * z);
    spts[gid] = make_float4(x, y, z, wv);

    unsigned short hx = bf16rn(x), hy = bf16rn(y), hz = bf16rn(z);
    unsigned short lx = bf16rn(x - bf2f(hx)), ly = bf16rn(y - bf2f(hy)), lz = bf16rn(z - bf2f(hz));
    unsigned short whi = bf16rn(wv), wlo = bf16rn(wv - bf2f(whi));

    uint4 f0, f1;
    f0.x = (unsigned)hx | ((unsigned)hy << 16);
    f0.y = (unsigned)hz | ((unsigned)lx << 16);
    f0.z = (unsigned)ly | ((unsigned)lz << 16);
    f0.w = (unsigned)hx | ((unsigned)hy << 16);
    f1.x = (unsigned)hz | ((unsigned)whi << 16);
    f1.y = (unsigned)wlo;
    f1.z = 0u; f1.w = 0u;
    uint4* fb = (uint4*)(featB + (size_t)gid * 16);
    fb[0] = f0; fb[1] = f1;

    const float* lb = logits + b * NC * NPTS;
    float l[NC];
    float mx = -1e30f;
    #pragma unroll
    for (int c = 0; c < NC; ++c) { l[c] = lb[c * NPTS + n]; mx = fmaxf(mx, l[c]); }
    float sum = 0.f;
    #pragma unroll
    for (int c = 0; c < NC; ++c) { l[c] = __expf(l[c] - mx); sum += l[c]; }
    float inv = 1.0f / sum;
    #pragma unroll
    for (int c = 0; c < NC; ++c) l[c] *= inv;

    float4* dst = probst + (size_t)gid * 4;
    dst[0] = make_float4(l[0], l[1], l[2], l[3]);
    dst[1] = make_float4(l[4], l[5], l[6], l[7]);
    dst[2] = make_float4(l[8], l[9], l[10], l[11]);
    dst[3] = make_float4(l[12], 0.f, 0.f, 0.f);   // pads contribute |0-0| = 0
}

// ---------------- kernel B: MFMA pre-filter + exact top-16 + loss ----------------
// 512 thr = 8 waves = one 32-row stripe; wave scans 32 col-tiles/pass.
// grid = NB * NPTS / SR = 1024 blocks -> 4 blocks/CU, 8 waves/SIMD.
__global__ __launch_bounds__(512, 8) void topk_loss_kernel(
    const unsigned short* __restrict__ featB, const float4* __restrict__ spts,
    const float* __restrict__ rgb, const float4* __restrict__ probst,
    float* __restrict__ partials)
{
    // one arena, phase-overlaid:
    //  [0,16640)        dscore f32 [32][130]
    //  [16640,24960)    didx   u16 [32][130]
    //  [24960,35200)    seg    u16 [32][8][20]
    //  [35200,35712)    segcnt u16 [32][8]
    //  [35712,35744)    wred   f32 [8]
    //  threshold-merge overlay: f32 [8][16][64] = 32768 B over [0,32768)
    __shared__ __align__(16) char smem[35744];
    float*          s_dscore = (float*)smem;
    unsigned short* s_didx   = (unsigned short*)(smem + 16640);
    unsigned short* s_seg    = (unsigned short*)(smem + 24960);
    unsigned short* s_segcnt = (unsigned short*)(smem + 35200);
    float*          s_wred   = (float*)(smem + 35712);
    float*          s_bk     = (float*)smem;              // overlay (pass-1 merge)

    const int tid = threadIdx.x;
    const int w = tid >> 6, lane = tid & 63;
    const int l31 = lane & 31, h = lane >> 5;
    const int b = blockIdx.x >> 8;                 // 256 blocks per batch
    const int nbase = (blockIdx.x & 255) * SR;
    const int sb = b * NPTS;

    // ---- A fragment (queries, split-bf16) in registers ----
    const float4 Q0 = spts[sb + nbase + l31];
    unsigned short qhx = bf16rn(Q0.x), qhy = bf16rn(Q0.y), qhz = bf16rn(Q0.z);
    unsigned short qlx = bf16rn(Q0.x - bf2f(qhx)), qly = bf16rn(Q0.y - bf2f(qhy)),
                   qlz = bf16rn(Q0.z - bf2f(qhz));
    const unsigned short ONE = 0x3F80;
    union { unsigned short u[8]; s16x8 v; } af;
    if (h == 0) {
        af.u[0] = qhx; af.u[1] = qhy; af.u[2] = qhz; af.u[3] = qhx;
        af.u[4] = qhy; af.u[5] = qhz; af.u[6] = qlx; af.u[7] = qly;
    } else {
        af.u[0] = qlz; af.u[1] = ONE; af.u[2] = ONE; af.u[3] = 0;
        af.u[4] = 0;   af.u[5] = 0;   af.u[6] = 0;   af.u[7] = 0;
    }

    f32x16 cz;
    #pragma unroll
    for (int i = 0; i < 16; ++i) cz[i] = 0.f;

    const unsigned short* fB = featB + (size_t)sb * 16;

    // ---- pass 1: per-(lane=column, r) running max via MFMA ----
    float bk[16];
    #pragma unroll
    for (int r = 0; r < 16; ++r) bk[r] = -3.0e38f;

    for (int i = 0; i < NT / 8; ++i) {
        int t = i * 8 + w;
        s16x8 bf = *(const s16x8*)(fB + (t * 32 + l31) * 16 + h * 8);
        f32x16 c = __builtin_amdgcn_mfma_f32_32x32x16_bf16(af.v, bf, cz, 0, 0, 0);
        #pragma unroll
        for (int r = 0; r < 16; ++r) bk[r] = fmaxf(bk[r], c[r]);
    }

    // ---- merge 8 waves' column maxes; thr = min over 8 buckets of top-2 ----
    #pragma unroll
    for (int r = 0; r < 16; ++r) s_bk[(w * 16 + r) * 64 + lane] = bk[r];
    __syncthreads();

    float thr[16];
    #pragma unroll
    for (int r = 0; r < 16; ++r) {
        float m = s_bk[r * 64 + lane];
        #pragma unroll
        for (int w2 = 1; w2 < 8; ++w2) m = fmaxf(m, s_bk[(w2 * 16 + r) * 64 + lane]);
        // bucket = column group {l31, l31^8, l31^16, l31^24}: top-2 of 4 column maxes
        float m1 = m, m2 = -3.0e38f;
        #pragma unroll
        for (int mk = 8; mk <= 16; mk <<= 1) {
            float p1 = __shfl_xor(m1, mk), p2 = __shfl_xor(m2, mk);
            float lo = fminf(m1, p1);
            m1 = fmaxf(m1, p1);
            m2 = fmaxf(lo, fmaxf(m2, p2));
        }
        // min of the 8 buckets' 2nd-maxes -> 16 distinct pts >= thr+MARGIN
        #pragma unroll
        for (int mk = 1; mk < 8; mk <<= 1) m2 = fminf(m2, __shfl_xor(m2, mk));
        thr[r] = m2 - MARGIN;
    }
    __syncthreads();                                // release overlay

    // ---- pass 2: collect candidates, atomic-free ballot-prefix append ----
    int cntr[16];
    #pragma unroll
    for (int r = 0; r < 16; ++r) cntr[r] = 0;

    const unsigned ltmask = (1u << l31) - 1u;
    for (int i = 0; i < NT / 8; ++i) {
        int t = i * 8 + w;
        s16x8 bf = *(const s16x8*)(fB + (t * 32 + l31) * 16 + h * 8);
        f32x16 c = __builtin_amdgcn_mfma_f32_32x32x16_bf16(af.v, bf, cz, 0, 0, 0);
        #pragma unroll
        for (int r = 0; r < 16; ++r) {
            bool pass = (c[r] >= thr[r]);
            ull mask = __ballot(pass);
            if (mask) {                             // wave-uniform SALU branch
                unsigned mh = (unsigned)(h ? (mask >> 32) : mask);
                if (pass) {
                    int row = (r & 3) + 8 * (r >> 2) + 4 * h;
                    int slot = cntr[r] + __popc(mh & ltmask);
                    if (slot < SEGCAP)
                        s_seg[(row * 8 + w) * SEGCAP + slot] =
                            (unsigned short)(t * 32 + l31);
                }
                cntr[r] += __popc(mh);
            }
        }
    }
    if (l31 == 0) {
        #pragma unroll
        for (int r = 0; r < 16; ++r) {
            int row = (r & 3) + 8 * (r >> 2) + 4 * h;
            s_segcnt[row * 8 + w] = (unsigned short)min(cntr[r], SEGCAP);
        }
    }
    __syncthreads();

    // ---- phase 3: compact + exact fp32 rescore (16 lanes per row) ----
    const int row = tid >> 4, i0 = tid & 15;
    const int nrow = nbase + row;
    int cw[8], off[8], cnt = 0;
    #pragma unroll
    for (int w2 = 0; w2 < 8; ++w2) {
        cw[w2] = s_segcnt[row * 8 + w2];
        off[w2] = cnt; cnt += cw[w2];
    }
    cnt = min(cnt, DCAP);

    const float4 Q = spts[sb + nrow];
    #pragma unroll
    for (int w2 = 0; w2 < 8; ++w2) {
        for (int k = i0; k < cw[w2]; k += 16) {
            int j = off[w2] + k;
            if (j < DCAP) {
                int p = s_seg[(row * 8 + w2) * SEGCAP + k];
                float4 P = spts[sb + p];
                float s = fmaf(Q.x, P.x, fmaf(Q.y, P.y, fmaf(Q.z, P.z, P.w)));
                s_dscore[row * DCAPP + j] = s;
                s_didx[row * DCAPP + j] = (unsigned short)p;
            }
        }
    }
    __syncthreads();

    // ---- rank-count selection + loss terms ----
    const float* rb = rgb + b * 3 * NPTS;
    float crx = rb[nrow], cry = rb[NPTS + nrow], crz = rb[2 * NPTS + nrow];
    const float4* cp = probst + (size_t)(sb + nrow) * 4;
    float4 cp0 = cp[0], cp1 = cp[1], cp2 = cp[2], cp3 = cp[3];

    float acc = 0.f;
    for (int j = i0; j < cnt; j += 16) {
        float sj = s_dscore[row * DCAPP + j];
        unsigned pj = s_didx[row * DCAPP + j];
        int rank = 0;
        for (int j2 = 0; j2 < cnt; ++j2) {
            float s2 = s_dscore[row * DCAPP + j2];
            unsigned p2 = s_didx[row * DCAPP + j2];
            rank += (int)((s2 > sj) | ((s2 == sj) & (p2 < pj)));  // low idx wins ties
        }
        if (rank < KTOP) {                          // exact top-16 member
            int p = (int)pj;
            float nrx = rb[p], nry = rb[NPTS + p], nrz = rb[2 * NPTS + p];
            const float4* np4 = probst + (size_t)(sb + p) * 4;
            float4 q0 = np4[0], q1 = np4[1], q2 = np4[2], q3 = np4[3];
            float dx = crx - nrx, dy = cry - nry, dz = crz - nrz;
            float rd = sqrtf(fmaf(dx, dx, fmaf(dy, dy, dz * dz)));
            float pd = fabsf(cp0.x-q0.x)+fabsf(cp0.y-q0.y)+fabsf(cp0.z-q0.z)+fabsf(cp0.w-q0.w)
                     + fabsf(cp1.x-q1.x)+fabsf(cp1.y-q1.y)+fabsf(cp1.z-q1.z)+fabsf(cp1.w-q1.w)
                     + fabsf(cp2.x-q2.x)+fabsf(cp2.y-q2.y)+fabsf(cp2.z-q2.z)+fabsf(cp2.w-q2.w)
                     + fabsf(cp3.x-q3.x)+fabsf(cp3.y-q3.y)+fabsf(cp3.z-q3.z)+fabsf(cp3.w-q3.w);
            acc = fmaf(__expf(-10.0f * rd), pd, acc);
        }
    }

    // fixed-tree deterministic reduce: wave -> block -> partials
    #pragma unroll
    for (int offv = 32; offv > 0; offv >>= 1) acc += __shfl_down(acc, offv);
    if (lane == 0) s_wred[w] = acc;
    __syncthreads();
    if (tid == 0) {
        float bs = 0.f;
        #pragma unroll
        for (int i = 0; i < 8; ++i) bs += s_wred[i];
        partials[blockIdx.x] = bs;
    }
}

// ---------------- kernel C: final reduce (1024 partials) ----------------
__global__ __launch_bounds__(256) void reduce_kernel(const float* __restrict__ partials,
                                                     float* __restrict__ out) {
    __shared__ float s[256];
    int tid = threadIdx.x;
    s[tid] = partials[tid] + partials[tid + 256] + partials[tid + 512] + partials[tid + 768];
    __syncthreads();
    if (tid < 128) s[tid] += s[tid + 128];
    __syncthreads();
    if (tid < 64) {
        float x = s[tid] + s[tid + 64];
        for (int off = 32; off > 0; off >>= 1) x += __shfl_down(x, off);
        if (tid == 0) out[0] = x * (1.0f / (float)(NB * NPTS * KTOP));
    }
}

extern "C" void kernel_launch(void* const* d_in, const int* in_sizes, int n_in,
                              void* d_out, int out_size, void* d_ws, size_t ws_size,
                              hipStream_t stream) {
    (void)in_sizes; (void)n_in; (void)out_size; (void)ws_size;
    const float* logits = (const float*)d_in[0];
    const float* xyz    = (const float*)d_in[1];
    const float* rgb    = (const float*)d_in[2];

    // workspace: probst 2MB | featB 1MB | spts 512KB | partials 4KB  (~3.5 MB)
    float4* probst = (float4*)d_ws;                              // 131072 f4
    unsigned short* featB = (unsigned short*)(probst + (size_t)NB * NPTS * 4);  // 512K u16
    float4* spts = (float4*)(featB + (size_t)NB * NPTS * 16);    // 32768 f4
    float* partials = (float*)(spts + NB * NPTS);                // 1024 f

    prep_kernel<<<NB * NPTS / 256, 256, 0, stream>>>(logits, xyz, featB, spts, probst);
    topk_loss_kernel<<<NB * NPTS / SR, 512, 0, stream>>>(featB, spts, rgb, probst, partials);
    reduce_kernel<<<1, 256, 0, stream>>>(partials, (float*)d_out);
}